// Round 2
// baseline (4187.909 us; speedup 1.0000x reference)
//
#include <hip/hip_runtime.h>
#include <math.h>

// Problem constants
constexpr int B  = 8;
constexpr int S  = 1024;
constexpr int E  = 512;
constexpr int H  = 8;
constexpr int D  = 64;
constexpr int FF = 2048;
constexpr int NL = 4;
constexpr float EPS = 1e-5f;

// ---------------------------------------------------------------------------
// grid-stride float4 copy (init x = src)
// ---------------------------------------------------------------------------
__global__ __launch_bounds__(256) void copy_kernel(const float4* __restrict__ in,
                                                   float4* __restrict__ out, int n4) {
    int i = blockIdx.x * blockDim.x + threadIdx.x;
    int stride = gridDim.x * blockDim.x;
    for (; i < n4; i += stride) out[i] = in[i];
}

// ---------------------------------------------------------------------------
// LayerNorm over last dim E=512. One block (256 thr) per row; 2 floats/thread.
// ---------------------------------------------------------------------------
__global__ __launch_bounds__(256) void ln_kernel(const float* __restrict__ x,
                                                 const float* __restrict__ g,
                                                 const float* __restrict__ b,
                                                 float* __restrict__ out) {
    const int row = blockIdx.x;
    const float* xr = x + (size_t)row * E;
    const int c = threadIdx.x * 2;
    float2 v = *(const float2*)(xr + c);
    float s  = v.x + v.y;
    float ss = v.x * v.x + v.y * v.y;
    #pragma unroll
    for (int off = 1; off < 64; off <<= 1) {
        s  += __shfl_xor(s, off);
        ss += __shfl_xor(ss, off);
    }
    __shared__ float red[8];
    const int wid = threadIdx.x >> 6, lane = threadIdx.x & 63;
    if (lane == 0) { red[wid] = s; red[4 + wid] = ss; }
    __syncthreads();
    s  = red[0] + red[1] + red[2] + red[3];
    ss = red[4] + red[5] + red[6] + red[7];
    const float mu   = s / (float)E;
    const float var  = ss / (float)E - mu * mu;
    const float rstd = rsqrtf(var + EPS);
    float2 gg = *(const float2*)(g + c);
    float2 bb = *(const float2*)(b + c);
    float2 o;
    o.x = (v.x - mu) * rstd * gg.x + bb.x;
    o.y = (v.y - mu) * rstd * gg.y + bb.y;
    *(float2*)(out + (size_t)row * E + c) = o;
}

// ---------------------------------------------------------------------------
// fp32 tiled GEMM: out[M,N] = epi(A[M,K] @ W[K,N] + bias[N])
// EPI: 0 = none, 1 = exact GELU, 2 = add residual
// tile 128x64, BK=16, 256 threads, 8x4 micro-tile
// ---------------------------------------------------------------------------
template <int EPI>
__global__ __launch_bounds__(256) void gemm_kernel(const float* __restrict__ A,
                                                   const float* __restrict__ W,
                                                   const float* __restrict__ bias,
                                                   const float* __restrict__ res,
                                                   float* __restrict__ out,
                                                   int M, int N, int K) {
    constexpr int BM = 128, BN = 64, BK = 16;
    __shared__ __align__(16) float As[BK][BM + 4];  // [k][m], stride 132
    __shared__ __align__(16) float Bs[BK][BN + 4];  // [k][n], stride 68

    const int bn = blockIdx.x, bm = blockIdx.y;
    const int t  = threadIdx.x;
    const int tr = t >> 4, tc = t & 15;  // 16 x 16

    float acc[8][4];
    #pragma unroll
    for (int i = 0; i < 8; ++i)
        #pragma unroll
        for (int j = 0; j < 4; ++j) acc[i][j] = 0.f;

    for (int kt = 0; kt < K; kt += BK) {
        __syncthreads();
        // stage A tile (128x16), transposed into As[k][m]
        #pragma unroll
        for (int l = 0; l < 2; ++l) {
            int f   = t + l * 256;          // float4 index 0..511
            int row = f >> 2, kq = f & 3;
            float4 a = *(const float4*)(A + (size_t)(bm * BM + row) * K + kt + kq * 4);
            As[kq * 4 + 0][row] = a.x;
            As[kq * 4 + 1][row] = a.y;
            As[kq * 4 + 2][row] = a.z;
            As[kq * 4 + 3][row] = a.w;
        }
        // stage B tile (16x64)
        {
            int row = t >> 4, cq = t & 15;
            float4 bv = *(const float4*)(W + (size_t)(kt + row) * N + bn * BN + cq * 4);
            *(float4*)(&Bs[row][cq * 4]) = bv;
        }
        __syncthreads();
        #pragma unroll
        for (int kk = 0; kk < BK; ++kk) {
            float4 a0 = *(const float4*)(&As[kk][tr * 8]);
            float4 a1 = *(const float4*)(&As[kk][tr * 8 + 4]);
            float4 b4 = *(const float4*)(&Bs[kk][tc * 4]);
            float av[8] = {a0.x, a0.y, a0.z, a0.w, a1.x, a1.y, a1.z, a1.w};
            float bv4[4] = {b4.x, b4.y, b4.z, b4.w};
            #pragma unroll
            for (int i = 0; i < 8; ++i)
                #pragma unroll
                for (int j = 0; j < 4; ++j)
                    acc[i][j] = fmaf(av[i], bv4[j], acc[i][j]);
        }
    }

    const int r0 = bm * BM + tr * 8;
    const int c0 = bn * BN + tc * 4;
    float4 bs = *(const float4*)(bias + c0);
    #pragma unroll
    for (int i = 0; i < 8; ++i) {
        float v[4] = {acc[i][0] + bs.x, acc[i][1] + bs.y,
                      acc[i][2] + bs.z, acc[i][3] + bs.w};
        if (EPI == 1) {
            #pragma unroll
            for (int j = 0; j < 4; ++j)
                v[j] = 0.5f * v[j] * (1.0f + erff(v[j] * 0.70710678118654752f));
        }
        if (EPI == 2) {
            float4 r4 = *(const float4*)(res + (size_t)(r0 + i) * N + c0);
            v[0] += r4.x; v[1] += r4.y; v[2] += r4.z; v[3] += r4.w;
        }
        float4 o4 = {v[0], v[1], v[2], v[3]};
        *(float4*)(out + (size_t)(r0 + i) * N + c0) = o4;
    }
}

// ---------------------------------------------------------------------------
// Flash-style attention, fp32.
// grid (qt=16, h=8, b=8), block 256 = 16x16 threads, 4x4 micro-tile.
// scores = (q.kT)*scale  ->  masked -> +edge_bias -> online softmax -> O += P.V
// ---------------------------------------------------------------------------
__global__ __launch_bounds__(256) void attn_kernel(const float* __restrict__ q,
                                                   const float* __restrict__ k,
                                                   const float* __restrict__ v,
                                                   const float* __restrict__ ebias,
                                                   const unsigned char* __restrict__ mask,
                                                   float* __restrict__ out) {
    const int qt = blockIdx.x, h = blockIdx.y, b = blockIdx.z;
    __shared__ __align__(16) float Qt[D][64];     // [d][r]
    __shared__ __align__(16) float KV[D * 64];    // K phase: [d][c]; V phase: swizzled [s][dv]
    __shared__ float Ps[64][65];                  // [r][s]

    const int t  = threadIdx.x;
    const int tr = t >> 4, tc = t & 15;
    const float scale = 0.125f;  // D^-0.5

    // stage Q transposed: Qt[d][r]
    {
        const int sr = t >> 2, dq = t & 3;
        const float* qp = q + ((size_t)(b * S) + qt * 64 + sr) * E + h * 64;
        #pragma unroll
        for (int it = 0; it < 4; ++it) {
            int d0 = (it * 4 + dq) * 4;
            float4 qv = *(const float4*)(qp + d0);
            Qt[d0 + 0][sr] = qv.x;
            Qt[d0 + 1][sr] = qv.y;
            Qt[d0 + 2][sr] = qv.z;
            Qt[d0 + 3][sr] = qv.w;
        }
    }

    float m_run[4], lsum[4], o[4][4];
    #pragma unroll
    for (int i = 0; i < 4; ++i) {
        m_run[i] = -INFINITY;
        lsum[i] = 0.f;
        #pragma unroll
        for (int j = 0; j < 4; ++j) o[i][j] = 0.f;
    }

    for (int kt = 0; kt < 16; ++kt) {
        __syncthreads();  // prev iter's PV done (and Qt staged, iter 0)
        // stage K transposed: KV[d][c], stride 64
        {
            const int sr = t >> 2, dq = t & 3;
            const float* kp = k + ((size_t)(b * S) + kt * 64 + sr) * E + h * 64;
            #pragma unroll
            for (int it = 0; it < 4; ++it) {
                int d0 = (it * 4 + dq) * 4;
                float4 kv4 = *(const float4*)(kp + d0);
                KV[(d0 + 0) * 64 + sr] = kv4.x;
                KV[(d0 + 1) * 64 + sr] = kv4.y;
                KV[(d0 + 2) * 64 + sr] = kv4.z;
                KV[(d0 + 3) * 64 + sr] = kv4.w;
            }
        }
        __syncthreads();

        // scores: sc[i][j] = sum_d Q[r][d] * K[c][d]
        float sc[4][4];
        #pragma unroll
        for (int i = 0; i < 4; ++i)
            #pragma unroll
            for (int j = 0; j < 4; ++j) sc[i][j] = 0.f;
        #pragma unroll 8
        for (int d = 0; d < 64; ++d) {
            float4 qv = *(const float4*)(&Qt[d][tr * 4]);
            float4 kv4 = *(const float4*)(&KV[d * 64 + tc * 4]);
            float qa[4] = {qv.x, qv.y, qv.z, qv.w};
            float ka[4] = {kv4.x, kv4.y, kv4.z, kv4.w};
            #pragma unroll
            for (int i = 0; i < 4; ++i)
                #pragma unroll
                for (int j = 0; j < 4; ++j)
                    sc[i][j] = fmaf(qa[i], ka[j], sc[i][j]);
        }

        // scale, pad-mask, +edge_bias
        const int r0 = qt * 64 + tr * 4;
        const int c0 = kt * 64 + tc * 4;
        uchar4 mk = *(const uchar4*)(mask + (size_t)b * S + c0);
        const float NEG = -3.4028234663852886e38f;  // finfo(f32).min
        #pragma unroll
        for (int i = 0; i < 4; ++i) {
            float4 bv = *(const float4*)(ebias + ((size_t)b * S + r0 + i) * S + c0);
            sc[i][0] = (mk.x ? NEG : sc[i][0] * scale) + bv.x;
            sc[i][1] = (mk.y ? NEG : sc[i][1] * scale) + bv.y;
            sc[i][2] = (mk.z ? NEG : sc[i][2] * scale) + bv.z;
            sc[i][3] = (mk.w ? NEG : sc[i][3] * scale) + bv.w;
        }

        // online softmax per row (reduce across the 16 tc lanes)
        #pragma unroll
        for (int i = 0; i < 4; ++i) {
            float mx = fmaxf(fmaxf(sc[i][0], sc[i][1]), fmaxf(sc[i][2], sc[i][3]));
            #pragma unroll
            for (int off = 1; off < 16; off <<= 1) mx = fmaxf(mx, __shfl_xor(mx, off));
            float mnew = fmaxf(m_run[i], mx);
            float corr = expf(m_run[i] - mnew);
            m_run[i] = mnew;
            float rs = 0.f;
            #pragma unroll
            for (int j = 0; j < 4; ++j) {
                sc[i][j] = expf(sc[i][j] - mnew);
                rs += sc[i][j];
            }
            #pragma unroll
            for (int off = 1; off < 16; off <<= 1) rs += __shfl_xor(rs, off);
            lsum[i] = lsum[i] * corr + rs;
            #pragma unroll
            for (int j = 0; j < 4; ++j) o[i][j] *= corr;
            #pragma unroll
            for (int j = 0; j < 4; ++j) Ps[tr * 4 + i][tc * 4 + j] = sc[i][j];
        }
        __syncthreads();  // done reading K, Ps written

        // stage V into KV with XOR swizzle on the float4-column index
        {
            const int sr = t >> 2, q4 = t & 3;
            const float* vp = v + ((size_t)(b * S) + kt * 64 + sr) * E + h * 64;
            #pragma unroll
            for (int it = 0; it < 4; ++it) {
                int qidx = it * 4 + q4;
                float4 vv = *(const float4*)(vp + qidx * 4);
                int qs = qidx ^ (sr & 15);
                *(float4*)(&KV[sr * 64 + qs * 4]) = vv;
            }
        }
        __syncthreads();  // V ready

        // O += P @ V
        #pragma unroll 8
        for (int s2 = 0; s2 < 64; ++s2) {
            int qs = tc ^ (s2 & 15);
            float4 vv = *(const float4*)(&KV[s2 * 64 + qs * 4]);
            float va[4] = {vv.x, vv.y, vv.z, vv.w};
            float pv[4] = {Ps[tr * 4 + 0][s2], Ps[tr * 4 + 1][s2],
                           Ps[tr * 4 + 2][s2], Ps[tr * 4 + 3][s2]};
            #pragma unroll
            for (int i = 0; i < 4; ++i)
                #pragma unroll
                for (int j = 0; j < 4; ++j)
                    o[i][j] = fmaf(pv[i], va[j], o[i][j]);
        }
    }

    // normalize + write
    #pragma unroll
    for (int i = 0; i < 4; ++i) {
        float inv = 1.0f / lsum[i];
        float4 ov = {o[i][0] * inv, o[i][1] * inv, o[i][2] * inv, o[i][3] * inv};
        *(float4*)(out + ((size_t)(b * S) + qt * 64 + tr * 4 + i) * E + h * 64 + tc * 4) = ov;
    }
}

// ---------------------------------------------------------------------------
extern "C" void kernel_launch(void* const* d_in, const int* in_sizes, int n_in,
                              void* d_out, int out_size, void* d_ws, size_t ws_size,
                              hipStream_t stream) {
    const float* src  = (const float*)d_in[0];
    const float* eb   = (const float*)d_in[1];
    const unsigned char* mask = (const unsigned char*)d_in[2];
    const float* Wq = (const float*)d_in[3];
    const float* bq = (const float*)d_in[4];
    const float* Wk = (const float*)d_in[5];
    const float* bk = (const float*)d_in[6];
    const float* Wv = (const float*)d_in[7];
    const float* bv = (const float*)d_in[8];
    const float* Wo = (const float*)d_in[9];
    const float* bo = (const float*)d_in[10];
    const float* ln1g = (const float*)d_in[11];
    const float* ln1b = (const float*)d_in[12];
    const float* ln2g = (const float*)d_in[13];
    const float* ln2b = (const float*)d_in[14];
    const float* W1 = (const float*)d_in[15];
    const float* b1 = (const float*)d_in[16];
    const float* W2 = (const float*)d_in[17];
    const float* b2 = (const float*)d_in[18];

    float* x  = (float*)d_out;      // residual stream lives in d_out
    float* ws = (float*)d_ws;

    const size_t BSE = (size_t)B * S * E;  // 4,194,304
    float* hbuf = ws;                 // [BSE]
    float* qb   = ws + BSE;           // [BSE]
    float* kb   = qb + BSE;           // [BSE]
    float* vb   = kb + BSE;           // [BSE]
    float* ab   = vb + BSE;           // [BSE]
    float* ffn  = qb;                 // overlay q..attn region: B*S*FF floats

    const int MROWS = B * S;          // 8192

    // x = src
    copy_kernel<<<2048, 256, 0, stream>>>((const float4*)src, (float4*)x, (int)(BSE / 4));

    dim3 blk(256);
    dim3 gEE(E / 64, MROWS / 128);    // N=512  -> (8, 64)
    dim3 gEF(FF / 64, MROWS / 128);   // N=2048 -> (32, 64)
    dim3 gAttn(S / 64, H, B);         // (16, 8, 8)

    for (int l = 0; l < NL; ++l) {
        const size_t oEE = (size_t)l * E * E;
        // h = LN1(x)
        ln_kernel<<<MROWS, blk, 0, stream>>>(x, ln1g + l * E, ln1b + l * E, hbuf);
        // q,k,v projections
        gemm_kernel<0><<<gEE, blk, 0, stream>>>(hbuf, Wq + oEE, bq + l * E, nullptr, qb, MROWS, E, E);
        gemm_kernel<0><<<gEE, blk, 0, stream>>>(hbuf, Wk + oEE, bk + l * E, nullptr, kb, MROWS, E, E);
        gemm_kernel<0><<<gEE, blk, 0, stream>>>(hbuf, Wv + oEE, bv + l * E, nullptr, vb, MROWS, E, E);
        // attention
        attn_kernel<<<gAttn, blk, 0, stream>>>(qb, kb, vb, eb, mask, ab);
        // x = x + attn @ Wo + bo
        gemm_kernel<2><<<gEE, blk, 0, stream>>>(ab, Wo + oEE, bo + l * E, x, x, MROWS, E, E);
        // h = LN2(x)
        ln_kernel<<<MROWS, blk, 0, stream>>>(x, ln2g + l * E, ln2b + l * E, hbuf);
        // ffn = gelu(h @ W1 + b1)
        gemm_kernel<1><<<gEF, blk, 0, stream>>>(hbuf, W1 + (size_t)l * E * FF, b1 + l * FF,
                                                nullptr, ffn, MROWS, FF, E);
        // x = x + ffn @ W2 + b2
        gemm_kernel<2><<<gEE, blk, 0, stream>>>(ffn, W2 + (size_t)l * FF * E, b2 + l * E,
                                                x, x, MROWS, E, FF);
    }
}

// Round 3
// 2602.846 us; speedup vs baseline: 1.6090x; 1.6090x over previous
//
#include <hip/hip_runtime.h>
#include <math.h>

// Problem constants
constexpr int B  = 8;
constexpr int S  = 1024;
constexpr int E  = 512;
constexpr int H  = 8;
constexpr int FF = 2048;
constexpr int NL = 4;
constexpr int M  = B * S;          // 8192 rows
constexpr float EPS = 1e-5f;

typedef __attribute__((ext_vector_type(8))) short short8;   // 8 bf16 = 4 VGPR
typedef __attribute__((ext_vector_type(4))) float f32x4;

__device__ __forceinline__ ushort f2bf(float x) {
    union { float f; unsigned u; } c; c.f = x;
    unsigned r = c.u + 0x7FFF + ((c.u >> 16) & 1);   // RNE
    return (ushort)(r >> 16);
}
__device__ __forceinline__ float bf2f(ushort h) {
    union { unsigned u; float f; } c; c.u = ((unsigned)h) << 16; return c.f;
}
// async global->LDS, 16B per lane; LDS dest = base + lane*16 (HW), src per-lane
__device__ __forceinline__ void gload16(const void* g, void* l) {
    __builtin_amdgcn_global_load_lds(
        (const __attribute__((address_space(1))) unsigned*)g,
        (__attribute__((address_space(3))) unsigned*)l, 16, 0, 0);
}

// ---------------------------------------------------------------------------
__global__ __launch_bounds__(256) void copy_kernel(const float4* __restrict__ in,
                                                   float4* __restrict__ out, int n4) {
    int i = blockIdx.x * blockDim.x + threadIdx.x;
    int stride = gridDim.x * blockDim.x;
    for (; i < n4; i += stride) out[i] = in[i];
}

// pack per-layer QKV bias: [L][1536] = concat(bq, bk, bv)
__global__ __launch_bounds__(256) void biaspack_kernel(const float* __restrict__ bq,
                                                       const float* __restrict__ bk,
                                                       const float* __restrict__ bv,
                                                       float* __restrict__ out) {
    int i = blockIdx.x * blockDim.x + threadIdx.x;
    if (i >= NL * 1536) return;
    int l = i / 1536, c = i % 1536;
    float v = (c < 512) ? bq[l * 512 + c]
            : (c < 1024) ? bk[l * 512 + c - 512]
                         : bv[l * 512 + c - 1024];
    out[i] = v;
}

// ---------------------------------------------------------------------------
// Weight prep: W[K][N] fp32 -> hi/lo bf16 planes in [N][K] (transposed) layout.
// tile 32x32, 256 threads.
// ---------------------------------------------------------------------------
__global__ __launch_bounds__(256) void wprep_kernel(const float* __restrict__ W,
                                                    ushort* __restrict__ hi,
                                                    ushort* __restrict__ lo,
                                                    int K, int N) {
    __shared__ float tl[32][33];
    const int n0 = blockIdx.x * 32, k0 = blockIdx.y * 32;
    const int t = threadIdx.x;
    const int tr = t >> 3, tq = t & 7;
    float4 v = *(const float4*)(W + (size_t)(k0 + tr) * N + n0 + tq * 4);
    tl[tr][tq * 4 + 0] = v.x; tl[tr][tq * 4 + 1] = v.y;
    tl[tr][tq * 4 + 2] = v.z; tl[tr][tq * 4 + 3] = v.w;
    __syncthreads();
    const int n = n0 + tr;
    ushort4 hv, lv;
    float a;
    a = tl[tq * 4 + 0][tr]; hv.x = f2bf(a); lv.x = f2bf(a - bf2f(hv.x));
    a = tl[tq * 4 + 1][tr]; hv.y = f2bf(a); lv.y = f2bf(a - bf2f(hv.y));
    a = tl[tq * 4 + 2][tr]; hv.z = f2bf(a); lv.z = f2bf(a - bf2f(hv.z));
    a = tl[tq * 4 + 3][tr]; hv.w = f2bf(a); lv.w = f2bf(a - bf2f(hv.w));
    *(ushort4*)(hi + (size_t)n * K + k0 + tq * 4) = hv;
    *(ushort4*)(lo + (size_t)n * K + k0 + tq * 4) = lv;
}

// ---------------------------------------------------------------------------
// LayerNorm -> split-bf16 hi/lo planes. One block per row.
// ---------------------------------------------------------------------------
__global__ __launch_bounds__(256) void ln_kernel(const float* __restrict__ x,
                                                 const float* __restrict__ g,
                                                 const float* __restrict__ b,
                                                 ushort* __restrict__ ohi,
                                                 ushort* __restrict__ olo) {
    const int row = blockIdx.x;
    const float* xr = x + (size_t)row * E;
    const int c = threadIdx.x * 2;
    float2 v = *(const float2*)(xr + c);
    float s  = v.x + v.y;
    float ss = v.x * v.x + v.y * v.y;
    #pragma unroll
    for (int off = 1; off < 64; off <<= 1) {
        s  += __shfl_xor(s, off);
        ss += __shfl_xor(ss, off);
    }
    __shared__ float red[8];
    const int wid = threadIdx.x >> 6, lane = threadIdx.x & 63;
    if (lane == 0) { red[wid] = s; red[4 + wid] = ss; }
    __syncthreads();
    s  = red[0] + red[1] + red[2] + red[3];
    ss = red[4] + red[5] + red[6] + red[7];
    const float mu   = s / (float)E;
    const float var  = ss / (float)E - mu * mu;
    const float rstd = rsqrtf(var + EPS);
    float2 gg = *(const float2*)(g + c);
    float2 bb = *(const float2*)(b + c);
    float ox = (v.x - mu) * rstd * gg.x + bb.x;
    float oy = (v.y - mu) * rstd * gg.y + bb.y;
    ushort2 hv, lv;
    hv.x = f2bf(ox); lv.x = f2bf(ox - bf2f(hv.x));
    hv.y = f2bf(oy); lv.y = f2bf(oy - bf2f(hv.y));
    *(ushort2*)(ohi + (size_t)row * E + c) = hv;
    *(ushort2*)(olo + (size_t)row * E + c) = lv;
}

// ---------------------------------------------------------------------------
// Split-bf16 MFMA GEMM:  out[M,N] = epi(A @ W^T + bias),
//   A given as hi/lo bf16 planes [M][K] row-major,
//   W given as hi/lo bf16 planes [N][K] (pre-transposed).
// acc += Ah*Wh + Ah*Wl + Al*Wh  (Markidis split, ~fp32-grade)
// BM=128 fixed, BN template (64/128), BK=64, 256 thr = 4 waves (2x2).
// EPI: 0 = fp32 out, 1 = exact GELU -> hi/lo planes, 2 = fp32 residual +=
// m97 structure: global_load_lds(16B) staging, fragment-major LDS, 2 barriers.
// ---------------------------------------------------------------------------
template <int BN, int EPI>
__global__ __launch_bounds__(256) void gemm_mfma(
    const ushort* __restrict__ Ahi, const ushort* __restrict__ Alo,
    const ushort* __restrict__ Bhi, const ushort* __restrict__ Blo,
    const float* __restrict__ bias,
    float* __restrict__ outf, ushort* __restrict__ ohi, ushort* __restrict__ olo,
    int K, int ldo)
{
    constexpr int NBF = BN / 16;       // B 16-col fragments per plane per kk
    constexpr int NF  = BN / 32;       // n-fragments per wave
    constexpr int TL  = 32 + NBF * 4;  // wave-loads per K-tile (A:32, B:NBF*4)
    __shared__ ushort lds[16384 + NBF * 2048];   // A 32KB + B (NBF*4KB)

    const int t = threadIdx.x;
    const int lane = t & 63, wid = t >> 6;
    const int wr = wid >> 1, wc = wid & 1;
    const int bn = blockIdx.x, bm = blockIdx.y;
    const int lrow = lane & 15, lhi = lane >> 4;

    f32x4 acc[4][NF];
    #pragma unroll
    for (int i = 0; i < 4; ++i)
        #pragma unroll
        for (int j = 0; j < NF; ++j) acc[i][j] = (f32x4)0.f;

    auto stage = [&](int kt) {
        #pragma unroll
        for (int i = 0; i < TL / 4; ++i) {
            int w = wid * (TL / 4) + i;
            const ushort* src; int dst;
            if (w < 32) {            // A fragments: plane p, mf 0..7, kk 0..1
                int p = w >> 4, mf = (w >> 1) & 7, kk = w & 1;
                int row = bm * 128 + mf * 16 + lrow;
                int k   = kt + kk * 32 + lhi * 8;
                src = (p ? Alo : Ahi) + (size_t)row * K + k;
                dst = (p * 16 + mf * 2 + kk) * 512;
            } else {                 // B fragments
                int w2 = w - 32;
                int p = w2 / (NBF * 2), r = w2 % (NBF * 2);
                int nf = r >> 1, kk = r & 1;
                int n = bn * BN + nf * 16 + lrow;
                int k = kt + kk * 32 + lhi * 8;
                src = (p ? Blo : Bhi) + (size_t)n * K + k;
                dst = 16384 + (p * NBF * 2 + nf * 2 + kk) * 512;
            }
            gload16(src, &lds[dst]);
        }
    };

    stage(0);
    const int lrd = lane * 8;
    for (int kt = 0; kt < K; kt += 64) {
        __syncthreads();            // staged tile visible (vmcnt drain at barrier)
        #pragma unroll
        for (int kk = 0; kk < 2; ++kk) {
            short8 ah[4], al[4], bh[NF], bl[NF];
            #pragma unroll
            for (int m_ = 0; m_ < 4; ++m_) {
                int mf = wr * 4 + m_;
                ah[m_] = *(const short8*)&lds[(mf * 2 + kk) * 512 + lrd];
                al[m_] = *(const short8*)&lds[(16 + mf * 2 + kk) * 512 + lrd];
            }
            #pragma unroll
            for (int n_ = 0; n_ < NF; ++n_) {
                int nf = wc * NF + n_;
                bh[n_] = *(const short8*)&lds[16384 + (nf * 2 + kk) * 512 + lrd];
                bl[n_] = *(const short8*)&lds[16384 + (NBF * 2 + nf * 2 + kk) * 512 + lrd];
            }
            #pragma unroll
            for (int m_ = 0; m_ < 4; ++m_)
                #pragma unroll
                for (int n_ = 0; n_ < NF; ++n_) {
                    acc[m_][n_] = __builtin_amdgcn_mfma_f32_16x16x32_bf16(ah[m_], bh[n_], acc[m_][n_], 0, 0, 0);
                    acc[m_][n_] = __builtin_amdgcn_mfma_f32_16x16x32_bf16(ah[m_], bl[n_], acc[m_][n_], 0, 0, 0);
                    acc[m_][n_] = __builtin_amdgcn_mfma_f32_16x16x32_bf16(al[m_], bh[n_], acc[m_][n_], 0, 0, 0);
                }
        }
        __syncthreads();            // all waves done reading LDS
        if (kt + 64 < K) stage(kt + 64);
    }

    // epilogue: C/D layout col=lane&15, row=(lane>>4)*4+reg [m89-verified]
    #pragma unroll
    for (int m_ = 0; m_ < 4; ++m_) {
        #pragma unroll
        for (int n_ = 0; n_ < NF; ++n_) {
            const int n  = bn * BN + wc * (BN / 2) + n_ * 16 + lrow;
            const int m0 = bm * 128 + wr * 64 + m_ * 16 + lhi * 4;
            const float bv = bias[n];
            #pragma unroll
            for (int r = 0; r < 4; ++r) {
                const int m = m0 + r;
                float v = acc[m_][n_][r] + bv;
                if (EPI == 0) outf[(size_t)m * ldo + n] = v;
                if (EPI == 1) {
                    float gl = 0.5f * v * (1.0f + erff(v * 0.70710678118654752f));
                    ushort hh = f2bf(gl);
                    ohi[(size_t)m * ldo + n] = hh;
                    olo[(size_t)m * ldo + n] = f2bf(gl - bf2f(hh));
                }
                if (EPI == 2) outf[(size_t)m * ldo + n] += v;
            }
        }
    }
}

// ---------------------------------------------------------------------------
// Flash-style attention, fp32 compute; q/k/v strided in the fused qkv buffer
// (row stride 1536); output written as split-bf16 hi/lo planes.
// ---------------------------------------------------------------------------
constexpr int QKV_LD = 1536;
__global__ __launch_bounds__(256) void attn_kernel(const float* __restrict__ q,
                                                   const float* __restrict__ k,
                                                   const float* __restrict__ v,
                                                   const float* __restrict__ ebias,
                                                   const unsigned char* __restrict__ mask,
                                                   ushort* __restrict__ ohi,
                                                   ushort* __restrict__ olo) {
    const int qt = blockIdx.x, h = blockIdx.y, b = blockIdx.z;
    __shared__ __align__(16) float Qt[64][64];    // [d][r]
    __shared__ __align__(16) float KV[64 * 64];   // K: [d][c]; V: swizzled [s][dv]
    __shared__ float Ps[64][65];

    const int t  = threadIdx.x;
    const int tr = t >> 4, tc = t & 15;
    const float scale = 0.125f;

    {
        const int sr = t >> 2, dq = t & 3;
        const float* qp = q + ((size_t)(b * S) + qt * 64 + sr) * QKV_LD + h * 64;
        #pragma unroll
        for (int it = 0; it < 4; ++it) {
            int d0 = (it * 4 + dq) * 4;
            float4 qv = *(const float4*)(qp + d0);
            Qt[d0 + 0][sr] = qv.x; Qt[d0 + 1][sr] = qv.y;
            Qt[d0 + 2][sr] = qv.z; Qt[d0 + 3][sr] = qv.w;
        }
    }

    float m_run[4], lsum[4], o[4][4];
    #pragma unroll
    for (int i = 0; i < 4; ++i) {
        m_run[i] = -INFINITY; lsum[i] = 0.f;
        #pragma unroll
        for (int j = 0; j < 4; ++j) o[i][j] = 0.f;
    }

    for (int kt = 0; kt < 16; ++kt) {
        __syncthreads();
        {
            const int sr = t >> 2, dq = t & 3;
            const float* kp = k + ((size_t)(b * S) + kt * 64 + sr) * QKV_LD + h * 64;
            #pragma unroll
            for (int it = 0; it < 4; ++it) {
                int d0 = (it * 4 + dq) * 4;
                float4 kv4 = *(const float4*)(kp + d0);
                KV[(d0 + 0) * 64 + sr] = kv4.x; KV[(d0 + 1) * 64 + sr] = kv4.y;
                KV[(d0 + 2) * 64 + sr] = kv4.z; KV[(d0 + 3) * 64 + sr] = kv4.w;
            }
        }
        __syncthreads();

        float sc[4][4];
        #pragma unroll
        for (int i = 0; i < 4; ++i)
            #pragma unroll
            for (int j = 0; j < 4; ++j) sc[i][j] = 0.f;
        #pragma unroll 8
        for (int d = 0; d < 64; ++d) {
            float4 qv = *(const float4*)(&Qt[d][tr * 4]);
            float4 kv4 = *(const float4*)(&KV[d * 64 + tc * 4]);
            float qa[4] = {qv.x, qv.y, qv.z, qv.w};
            float ka[4] = {kv4.x, kv4.y, kv4.z, kv4.w};
            #pragma unroll
            for (int i = 0; i < 4; ++i)
                #pragma unroll
                for (int j = 0; j < 4; ++j)
                    sc[i][j] = fmaf(qa[i], ka[j], sc[i][j]);
        }

        const int r0 = qt * 64 + tr * 4;
        const int c0 = kt * 64 + tc * 4;
        uchar4 mk = *(const uchar4*)(mask + (size_t)b * S + c0);
        const float NEG = -3.4028234663852886e38f;
        #pragma unroll
        for (int i = 0; i < 4; ++i) {
            float4 bv = *(const float4*)(ebias + ((size_t)b * S + r0 + i) * S + c0);
            sc[i][0] = (mk.x ? NEG : sc[i][0] * scale) + bv.x;
            sc[i][1] = (mk.y ? NEG : sc[i][1] * scale) + bv.y;
            sc[i][2] = (mk.z ? NEG : sc[i][2] * scale) + bv.z;
            sc[i][3] = (mk.w ? NEG : sc[i][3] * scale) + bv.w;
        }

        #pragma unroll
        for (int i = 0; i < 4; ++i) {
            float mx = fmaxf(fmaxf(sc[i][0], sc[i][1]), fmaxf(sc[i][2], sc[i][3]));
            #pragma unroll
            for (int off = 1; off < 16; off <<= 1) mx = fmaxf(mx, __shfl_xor(mx, off));
            float mnew = fmaxf(m_run[i], mx);
            float corr = expf(m_run[i] - mnew);
            m_run[i] = mnew;
            float rs = 0.f;
            #pragma unroll
            for (int j = 0; j < 4; ++j) { sc[i][j] = expf(sc[i][j] - mnew); rs += sc[i][j]; }
            #pragma unroll
            for (int off = 1; off < 16; off <<= 1) rs += __shfl_xor(rs, off);
            lsum[i] = lsum[i] * corr + rs;
            #pragma unroll
            for (int j = 0; j < 4; ++j) o[i][j] *= corr;
            #pragma unroll
            for (int j = 0; j < 4; ++j) Ps[tr * 4 + i][tc * 4 + j] = sc[i][j];
        }
        __syncthreads();

        {
            const int sr = t >> 2, q4 = t & 3;
            const float* vp = v + ((size_t)(b * S) + kt * 64 + sr) * QKV_LD + h * 64;
            #pragma unroll
            for (int it = 0; it < 4; ++it) {
                int qidx = it * 4 + q4;
                float4 vv = *(const float4*)(vp + qidx * 4);
                int qs = qidx ^ (sr & 15);
                *(float4*)(&KV[sr * 64 + qs * 4]) = vv;
            }
        }
        __syncthreads();

        #pragma unroll 8
        for (int s2 = 0; s2 < 64; ++s2) {
            int qs = tc ^ (s2 & 15);
            float4 vv = *(const float4*)(&KV[s2 * 64 + qs * 4]);
            float va[4] = {vv.x, vv.y, vv.z, vv.w};
            float pv[4] = {Ps[tr * 4 + 0][s2], Ps[tr * 4 + 1][s2],
                           Ps[tr * 4 + 2][s2], Ps[tr * 4 + 3][s2]};
            #pragma unroll
            for (int i = 0; i < 4; ++i)
                #pragma unroll
                for (int j = 0; j < 4; ++j)
                    o[i][j] = fmaf(pv[i], va[j], o[i][j]);
        }
    }

    #pragma unroll
    for (int i = 0; i < 4; ++i) {
        float inv = 1.0f / lsum[i];
        size_t idx = ((size_t)(b * S) + qt * 64 + tr * 4 + i) * E + h * 64 + tc * 4;
        ushort4 hv, lv;
        float a;
        a = o[i][0] * inv; hv.x = f2bf(a); lv.x = f2bf(a - bf2f(hv.x));
        a = o[i][1] * inv; hv.y = f2bf(a); lv.y = f2bf(a - bf2f(hv.y));
        a = o[i][2] * inv; hv.z = f2bf(a); lv.z = f2bf(a - bf2f(hv.z));
        a = o[i][3] * inv; hv.w = f2bf(a); lv.w = f2bf(a - bf2f(hv.w));
        *(ushort4*)(ohi + idx) = hv;
        *(ushort4*)(olo + idx) = lv;
    }
}

// ---------------------------------------------------------------------------
extern "C" void kernel_launch(void* const* d_in, const int* in_sizes, int n_in,
                              void* d_out, int out_size, void* d_ws, size_t ws_size,
                              hipStream_t stream) {
    const float* src  = (const float*)d_in[0];
    const float* eb   = (const float*)d_in[1];
    const unsigned char* mask = (const unsigned char*)d_in[2];
    const float* Wq = (const float*)d_in[3];
    const float* bq = (const float*)d_in[4];
    const float* Wk = (const float*)d_in[5];
    const float* bk = (const float*)d_in[6];
    const float* Wv = (const float*)d_in[7];
    const float* bv = (const float*)d_in[8];
    const float* Wo = (const float*)d_in[9];
    const float* bo = (const float*)d_in[10];
    const float* ln1g = (const float*)d_in[11];
    const float* ln1b = (const float*)d_in[12];
    const float* ln2g = (const float*)d_in[13];
    const float* ln2b = (const float*)d_in[14];
    const float* W1 = (const float*)d_in[15];
    const float* b1 = (const float*)d_in[16];
    const float* W2 = (const float*)d_in[17];
    const float* b2 = (const float*)d_in[18];

    float* x = (float*)d_out;                 // residual stream in d_out

    // ws layout (bytes). Per-layer weight planes: qkv[1536][512] | o[512][512]
    // | w1[2048][512] | w2[512][2048]  = 3,145,728 bf16 per plane.
    char* wsb = (char*)d_ws;
    ushort* w_hi = (ushort*)(wsb);
    ushort* w_lo = (ushort*)(wsb + 6291456);
    float*  bqkv = (float*) (wsb + 12582912);           // [L][1536]
    ushort* h_hi = (ushort*)(wsb + 12607488);           // [M][512]
    ushort* h_lo = (ushort*)(wsb + 20996096);
    char*  region = wsb + 29384704;                      // 67,108,864 B
    float*  qkv  = (float*) region;                      // [M][1536]
    ushort* ab_hi = (ushort*)(region + 50331648);        // [M][512]
    ushort* ab_lo = (ushort*)(region + 58720256);
    ushort* g_hi = (ushort*)(region);                    // [M][2048] overlay
    ushort* g_lo = (ushort*)(region + 33554432);

    constexpr size_t OFF_O = 786432;     // ushort offsets within a plane
    constexpr size_t OFF_1 = 1048576;
    constexpr size_t OFF_2 = 2097152;

    dim3 blk(256);
    copy_kernel<<<2048, blk, 0, stream>>>((const float4*)src, (float4*)x, M * E / 4);
    biaspack_kernel<<<24, blk, 0, stream>>>(bq, bk, bv, bqkv);

    for (int l = 0; l < NL; ++l) {
        const size_t oEE = (size_t)l * E * E;
        // weight prep (transpose + split) for this layer
        wprep_kernel<<<dim3(16, 16), blk, 0, stream>>>(Wq + oEE, w_hi,          w_lo,          512, 512);
        wprep_kernel<<<dim3(16, 16), blk, 0, stream>>>(Wk + oEE, w_hi + 262144, w_lo + 262144, 512, 512);
        wprep_kernel<<<dim3(16, 16), blk, 0, stream>>>(Wv + oEE, w_hi + 524288, w_lo + 524288, 512, 512);
        wprep_kernel<<<dim3(16, 16), blk, 0, stream>>>(Wo + oEE, w_hi + OFF_O,  w_lo + OFF_O,  512, 512);
        wprep_kernel<<<dim3(64, 16), blk, 0, stream>>>(W1 + (size_t)l * E * FF, w_hi + OFF_1, w_lo + OFF_1, 512, 2048);
        wprep_kernel<<<dim3(16, 64), blk, 0, stream>>>(W2 + (size_t)l * FF * E, w_hi + OFF_2, w_lo + OFF_2, 2048, 512);

        // h = LN1(x) -> split planes
        ln_kernel<<<M, blk, 0, stream>>>(x, ln1g + l * E, ln1b + l * E, h_hi, h_lo);
        // fused QKV projection (N=1536)
        gemm_mfma<128, 0><<<dim3(12, 64), blk, 0, stream>>>(h_hi, h_lo, w_hi, w_lo,
            bqkv + l * 1536, qkv, nullptr, nullptr, 512, 1536);
        // attention -> ab planes
        attn_kernel<<<dim3(16, 8, 8), blk, 0, stream>>>(qkv, qkv + 512, qkv + 1024,
            eb, mask, ab_hi, ab_lo);
        // x += attn @ Wo + bo
        gemm_mfma<64, 2><<<dim3(8, 64), blk, 0, stream>>>(ab_hi, ab_lo,
            w_hi + OFF_O, w_lo + OFF_O, bo + l * E, x, nullptr, nullptr, 512, 512);
        // h2 = LN2(x)
        ln_kernel<<<M, blk, 0, stream>>>(x, ln2g + l * E, ln2b + l * E, h_hi, h_lo);
        // gelu(h2 @ W1 + b1) -> split planes
        gemm_mfma<128, 1><<<dim3(16, 64), blk, 0, stream>>>(h_hi, h_lo,
            w_hi + OFF_1, w_lo + OFF_1, b1 + l * FF, nullptr, g_hi, g_lo, 512, 2048);
        // x += ffn @ W2 + b2
        gemm_mfma<64, 2><<<dim3(8, 64), blk, 0, stream>>>(g_hi, g_lo,
            w_hi + OFF_2, w_lo + OFF_2, b2 + l * E, x, nullptr, nullptr, 2048, 512);
    }
}

// Round 4
// 1980.264 us; speedup vs baseline: 2.1148x; 1.3144x over previous
//
#include <hip/hip_runtime.h>
#include <math.h>

// Problem constants
constexpr int B  = 8;
constexpr int S  = 1024;
constexpr int E  = 512;
constexpr int H  = 8;
constexpr int FF = 2048;
constexpr int NL = 4;
constexpr int M  = B * S;          // 8192 rows
constexpr float EPS = 1e-5f;

typedef __attribute__((ext_vector_type(8))) short short8;   // 8 bf16 = 4 VGPR
typedef __attribute__((ext_vector_type(4))) float f32x4;

__device__ __forceinline__ ushort f2bf(float x) {
    union { float f; unsigned u; } c; c.f = x;
    unsigned r = c.u + 0x7FFF + ((c.u >> 16) & 1);   // RNE
    return (ushort)(r >> 16);
}
__device__ __forceinline__ float bf2f(ushort h) {
    union { unsigned u; float f; } c; c.u = ((unsigned)h) << 16; return c.f;
}
// async global->LDS, 16B per lane; LDS dest = base + lane*16 (HW), src per-lane
__device__ __forceinline__ void gload16(const void* g, void* l) {
    __builtin_amdgcn_global_load_lds(
        (const __attribute__((address_space(1))) unsigned*)g,
        (__attribute__((address_space(3))) unsigned*)l, 16, 0, 0);
}

// ---------------------------------------------------------------------------
__global__ __launch_bounds__(256) void copy_kernel(const float4* __restrict__ in,
                                                   float4* __restrict__ out, int n4) {
    int i = blockIdx.x * blockDim.x + threadIdx.x;
    int stride = gridDim.x * blockDim.x;
    for (; i < n4; i += stride) out[i] = in[i];
}

// pack per-layer QKV bias: [L][1536] = concat(bq, bk, bv)
__global__ __launch_bounds__(256) void biaspack_kernel(const float* __restrict__ bq,
                                                       const float* __restrict__ bk,
                                                       const float* __restrict__ bv,
                                                       float* __restrict__ out) {
    int i = blockIdx.x * blockDim.x + threadIdx.x;
    if (i >= NL * 1536) return;
    int l = i / 1536, c = i % 1536;
    float v = (c < 512) ? bq[l * 512 + c]
            : (c < 1024) ? bk[l * 512 + c - 512]
                         : bv[l * 512 + c - 1024];
    out[i] = v;
}

// ---------------------------------------------------------------------------
// Weight prep: W[K][N] fp32 -> hi/lo bf16 planes in [N][K] (transposed) layout.
// ---------------------------------------------------------------------------
__global__ __launch_bounds__(256) void wprep_kernel(const float* __restrict__ W,
                                                    ushort* __restrict__ hi,
                                                    ushort* __restrict__ lo,
                                                    int K, int N) {
    __shared__ float tl[32][33];
    const int n0 = blockIdx.x * 32, k0 = blockIdx.y * 32;
    const int t = threadIdx.x;
    const int tr = t >> 3, tq = t & 7;
    float4 v = *(const float4*)(W + (size_t)(k0 + tr) * N + n0 + tq * 4);
    tl[tr][tq * 4 + 0] = v.x; tl[tr][tq * 4 + 1] = v.y;
    tl[tr][tq * 4 + 2] = v.z; tl[tr][tq * 4 + 3] = v.w;
    __syncthreads();
    const int n = n0 + tr;
    ushort4 hv, lv;
    float a;
    a = tl[tq * 4 + 0][tr]; hv.x = f2bf(a); lv.x = f2bf(a - bf2f(hv.x));
    a = tl[tq * 4 + 1][tr]; hv.y = f2bf(a); lv.y = f2bf(a - bf2f(hv.y));
    a = tl[tq * 4 + 2][tr]; hv.z = f2bf(a); lv.z = f2bf(a - bf2f(hv.z));
    a = tl[tq * 4 + 3][tr]; hv.w = f2bf(a); lv.w = f2bf(a - bf2f(hv.w));
    *(ushort4*)(hi + (size_t)n * K + k0 + tq * 4) = hv;
    *(ushort4*)(lo + (size_t)n * K + k0 + tq * 4) = lv;
}

// ---------------------------------------------------------------------------
// LayerNorm -> split-bf16 hi/lo planes. One block per row.
// ---------------------------------------------------------------------------
__global__ __launch_bounds__(256) void ln_kernel(const float* __restrict__ x,
                                                 const float* __restrict__ g,
                                                 const float* __restrict__ b,
                                                 ushort* __restrict__ ohi,
                                                 ushort* __restrict__ olo) {
    const int row = blockIdx.x;
    const float* xr = x + (size_t)row * E;
    const int c = threadIdx.x * 2;
    float2 v = *(const float2*)(xr + c);
    float s  = v.x + v.y;
    float ss = v.x * v.x + v.y * v.y;
    #pragma unroll
    for (int off = 1; off < 64; off <<= 1) {
        s  += __shfl_xor(s, off);
        ss += __shfl_xor(ss, off);
    }
    __shared__ float red[8];
    const int wid = threadIdx.x >> 6, lane = threadIdx.x & 63;
    if (lane == 0) { red[wid] = s; red[4 + wid] = ss; }
    __syncthreads();
    s  = red[0] + red[1] + red[2] + red[3];
    ss = red[4] + red[5] + red[6] + red[7];
    const float mu   = s / (float)E;
    const float var  = ss / (float)E - mu * mu;
    const float rstd = rsqrtf(var + EPS);
    float2 gg = *(const float2*)(g + c);
    float2 bb = *(const float2*)(b + c);
    float ox = (v.x - mu) * rstd * gg.x + bb.x;
    float oy = (v.y - mu) * rstd * gg.y + bb.y;
    ushort2 hv, lv;
    hv.x = f2bf(ox); lv.x = f2bf(ox - bf2f(hv.x));
    hv.y = f2bf(oy); lv.y = f2bf(oy - bf2f(hv.y));
    *(ushort2*)(ohi + (size_t)row * E + c) = hv;
    *(ushort2*)(olo + (size_t)row * E + c) = lv;
}

// ---------------------------------------------------------------------------
// Split-bf16 MFMA GEMM (verified m97-style structure).
// EPI: 1 = exact GELU -> hi/lo planes, 2 = fp32 residual +=,
//      3 = QKV: cols<1024 -> split planes (ld 1024), cols>=1024 -> V bf16 plane
// ---------------------------------------------------------------------------
template <int BN, int EPI>
__global__ __launch_bounds__(256) void gemm_mfma(
    const ushort* __restrict__ Ahi, const ushort* __restrict__ Alo,
    const ushort* __restrict__ Bhi, const ushort* __restrict__ Blo,
    const float* __restrict__ bias,
    float* __restrict__ outf, ushort* __restrict__ ohi, ushort* __restrict__ olo,
    int K, int ldo)
{
    constexpr int NBF = BN / 16;
    constexpr int NF  = BN / 32;
    constexpr int TL  = 32 + NBF * 4;
    __shared__ ushort lds[16384 + NBF * 2048];

    const int t = threadIdx.x;
    const int lane = t & 63, wid = t >> 6;
    const int wr = wid >> 1, wc = wid & 1;
    const int bn = blockIdx.x, bm = blockIdx.y;
    const int lrow = lane & 15, lhi = lane >> 4;

    f32x4 acc[4][NF];
    #pragma unroll
    for (int i = 0; i < 4; ++i)
        #pragma unroll
        for (int j = 0; j < NF; ++j) acc[i][j] = (f32x4)0.f;

    auto stage = [&](int kt) {
        #pragma unroll
        for (int i = 0; i < TL / 4; ++i) {
            int w = wid * (TL / 4) + i;
            const ushort* src; int dst;
            if (w < 32) {
                int p = w >> 4, mf = (w >> 1) & 7, kk = w & 1;
                int row = bm * 128 + mf * 16 + lrow;
                int k   = kt + kk * 32 + lhi * 8;
                src = (p ? Alo : Ahi) + (size_t)row * K + k;
                dst = (p * 16 + mf * 2 + kk) * 512;
            } else {
                int w2 = w - 32;
                int p = w2 / (NBF * 2), r = w2 % (NBF * 2);
                int nf = r >> 1, kk = r & 1;
                int n = bn * BN + nf * 16 + lrow;
                int k = kt + kk * 32 + lhi * 8;
                src = (p ? Blo : Bhi) + (size_t)n * K + k;
                dst = 16384 + (p * NBF * 2 + nf * 2 + kk) * 512;
            }
            gload16(src, &lds[dst]);
        }
    };

    stage(0);
    const int lrd = lane * 8;
    for (int kt = 0; kt < K; kt += 64) {
        __syncthreads();
        #pragma unroll
        for (int kk = 0; kk < 2; ++kk) {
            short8 ah[4], al[4], bh[NF], bl[NF];
            #pragma unroll
            for (int m_ = 0; m_ < 4; ++m_) {
                int mf = wr * 4 + m_;
                ah[m_] = *(const short8*)&lds[(mf * 2 + kk) * 512 + lrd];
                al[m_] = *(const short8*)&lds[(16 + mf * 2 + kk) * 512 + lrd];
            }
            #pragma unroll
            for (int n_ = 0; n_ < NF; ++n_) {
                int nf = wc * NF + n_;
                bh[n_] = *(const short8*)&lds[16384 + (nf * 2 + kk) * 512 + lrd];
                bl[n_] = *(const short8*)&lds[16384 + (NBF * 2 + nf * 2 + kk) * 512 + lrd];
            }
            #pragma unroll
            for (int m_ = 0; m_ < 4; ++m_)
                #pragma unroll
                for (int n_ = 0; n_ < NF; ++n_) {
                    acc[m_][n_] = __builtin_amdgcn_mfma_f32_16x16x32_bf16(ah[m_], bh[n_], acc[m_][n_], 0, 0, 0);
                    acc[m_][n_] = __builtin_amdgcn_mfma_f32_16x16x32_bf16(ah[m_], bl[n_], acc[m_][n_], 0, 0, 0);
                    acc[m_][n_] = __builtin_amdgcn_mfma_f32_16x16x32_bf16(al[m_], bh[n_], acc[m_][n_], 0, 0, 0);
                }
        }
        __syncthreads();
        if (kt + 64 < K) stage(kt + 64);
    }

    #pragma unroll
    for (int m_ = 0; m_ < 4; ++m_) {
        #pragma unroll
        for (int n_ = 0; n_ < NF; ++n_) {
            const int n  = bn * BN + wc * (BN / 2) + n_ * 16 + lrow;
            const int m0 = bm * 128 + wr * 64 + m_ * 16 + lhi * 4;
            const float bv = bias[n];
            #pragma unroll
            for (int r = 0; r < 4; ++r) {
                const int m = m0 + r;
                float v = acc[m_][n_][r] + bv;
                if (EPI == 1) {
                    float gl = 0.5f * v * (1.0f + erff(v * 0.70710678118654752f));
                    ushort hh = f2bf(gl);
                    ohi[(size_t)m * ldo + n] = hh;
                    olo[(size_t)m * ldo + n] = f2bf(gl - bf2f(hh));
                }
                if (EPI == 2) outf[(size_t)m * ldo + n] += v;
                if (EPI == 3) {
                    if (n < 1024) {
                        ushort hh = f2bf(v);
                        ohi[(size_t)m * 1024 + n] = hh;
                        olo[(size_t)m * 1024 + n] = f2bf(v - bf2f(hh));
                    } else {
                        ((ushort*)outf)[(size_t)m * 512 + (n - 1024)] = f2bf(v);
                    }
                }
            }
        }
    }
}

// ---------------------------------------------------------------------------
// V transpose: vpl [B*S][512] bf16 -> vT [(b*512 + h*64 + d)][S] bf16.
// 64x64 tiles via swizzled LDS.
// ---------------------------------------------------------------------------
__global__ __launch_bounds__(256) void vtrans_kernel(const ushort* __restrict__ vpl,
                                                     ushort* __restrict__ vT) {
    __shared__ ushort tl[4096];   // [s 64][c 64], byte = s*128 + c*2, ^((s&7)<<4)
    const int s0 = blockIdx.x * 64, c0 = blockIdx.y * 64, b = blockIdx.z;
    const int t = threadIdx.x;
    {
        const int r = t >> 3, ch = t & 7;
        #pragma unroll
        for (int p = 0; p < 2; ++p) {
            int rr = r + p * 32;
            short8 vv = *(const short8*)(vpl + ((size_t)b * S + s0 + rr) * 512 + c0 + ch * 8);
            int byte = (rr * 128 + ch * 16) ^ ((rr & 7) << 4);
            *(short8*)((char*)tl + byte) = vv;
        }
    }
    __syncthreads();
    {
        const int sj = t & 7, cc0 = t >> 3;
        #pragma unroll
        for (int p = 0; p < 2; ++p) {
            int cc = cc0 + p * 32;
            short8 ov;
            #pragma unroll
            for (int k2 = 0; k2 < 8; ++k2) {
                int s = sj * 8 + k2;
                int byte = (s * 128 + cc * 2) ^ ((s & 7) << 4);
                ov[k2] = (short)*(const ushort*)((const char*)tl + byte);
            }
            *(short8*)(vT + ((size_t)b * 512 + c0 + cc) * S + s0 + sj * 8) = ov;
        }
    }
}

// ---------------------------------------------------------------------------
// MFMA flash attention. Grid (16 qtiles, H, B), 256 thr = 4 waves.
// Wave w owns 16 q-rows. Per 64-col k-tile:
//   S = Q K^T (Markidis split, 24 MFMA) -> mask/scale/+bias -> online softmax
//   -> P bf16 via swizzled per-wave LDS strip -> O += P V (8 MFMA).
// Q/K from split planes qkh/qkl [M][1024]; V from vT [B*E][S] bf16.
// Out: split planes [M][E].
// ---------------------------------------------------------------------------
__global__ __launch_bounds__(256) void attn_mfma(
    const ushort* __restrict__ qkh, const ushort* __restrict__ qkl,
    const ushort* __restrict__ vT,
    const float* __restrict__ ebias, const unsigned char* __restrict__ mask,
    ushort* __restrict__ ohi, ushort* __restrict__ olo)
{
    const int qt = blockIdx.x, h = blockIdx.y, b = blockIdx.z;
    const int t = threadIdx.x, lane = t & 63, wid = t >> 6;
    const int lr = lane & 15, lh = lane >> 4;
    const float scale = 0.125f;
    const float NEG = -3.4028234663852886e38f;

    // LDS (u16 units): Khi [sf*2+ks]*512 | Klo +4096 | V +8192 [df*2+ss]*512
    //                  | P +12288 + wid*1024 (swizzled strip [16][64])
    __shared__ ushort lds[16384];

    // Q fragments (A-layout), whole kernel in regs
    short8 qh[2], ql[2];
    {
        const size_t qrow = (size_t)b * S + qt * 64 + wid * 16 + lr;
        const int qc = h * 64 + lh * 8;
        #pragma unroll
        for (int ks = 0; ks < 2; ++ks) {
            qh[ks] = *(const short8*)(qkh + qrow * 1024 + qc + ks * 32);
            ql[ks] = *(const short8*)(qkl + qrow * 1024 + qc + ks * 32);
        }
    }

    f32x4 o[4];
    float mrun[4], lsum[4];
    #pragma unroll
    for (int j = 0; j < 4; ++j) { mrun[j] = -INFINITY; lsum[j] = 0.f; }
    #pragma unroll
    for (int df = 0; df < 4; ++df) o[df] = (f32x4)0.f;

    auto stage = [&](int kt) {
        #pragma unroll
        for (int i = 0; i < 6; ++i) {
            int f = wid * 6 + i;
            const ushort* src; int dst;
            if (f < 8) {                 // K hi
                int sf = f >> 1, ks = f & 1;
                src = qkh + ((size_t)b * S + kt * 64 + sf * 16 + lr) * 1024
                          + 512 + h * 64 + ks * 32 + lh * 8;
                dst = (sf * 2 + ks) * 512;
            } else if (f < 16) {         // K lo
                int f2 = f - 8, sf = f2 >> 1, ks = f2 & 1;
                src = qkl + ((size_t)b * S + kt * 64 + sf * 16 + lr) * 1024
                          + 512 + h * 64 + ks * 32 + lh * 8;
                dst = 4096 + (sf * 2 + ks) * 512;
            } else {                     // V (B-layout from vT)
                int f2 = f - 16, df = f2 >> 1, ss = f2 & 1;
                src = vT + ((size_t)(b * 8 + h) * 64 + df * 16 + lr) * S
                         + kt * 64 + ss * 32 + lh * 8;
                dst = 8192 + (df * 2 + ss) * 512;
            }
            gload16(src, &lds[dst]);
        }
    };

    char* pstrip = (char*)lds + 24576 + wid * 2048;
    const int q0 = qt * 64 + wid * 16 + lh * 4;   // q row (in S) of this lane's regs

    stage(0);
    for (int kt = 0; kt < 16; ++kt) {
        __syncthreads();   // staged K/V visible (vmcnt drained at barrier)

        // --- QK^T (split, 3 MFMA per fragment) ---
        f32x4 sc[4];
        #pragma unroll
        for (int sf = 0; sf < 4; ++sf) sc[sf] = (f32x4)0.f;
        #pragma unroll
        for (int ks = 0; ks < 2; ++ks)
            #pragma unroll
            for (int sf = 0; sf < 4; ++sf) {
                short8 kh = *(const short8*)&lds[(sf * 2 + ks) * 512 + lane * 8];
                short8 kl = *(const short8*)&lds[4096 + (sf * 2 + ks) * 512 + lane * 8];
                sc[sf] = __builtin_amdgcn_mfma_f32_16x16x32_bf16(qh[ks], kh, sc[sf], 0, 0, 0);
                sc[sf] = __builtin_amdgcn_mfma_f32_16x16x32_bf16(qh[ks], kl, sc[sf], 0, 0, 0);
                sc[sf] = __builtin_amdgcn_mfma_f32_16x16x32_bf16(ql[ks], kh, sc[sf], 0, 0, 0);
            }

        // --- mask, scale, +edge_bias (C-layout: row lh*4+j, col sf*16+lr) ---
        float scf[4][4];
        #pragma unroll
        for (int sf = 0; sf < 4; ++sf) {
            const int col = kt * 64 + sf * 16 + lr;
            const unsigned char mk = mask[(size_t)b * S + col];
            #pragma unroll
            for (int j = 0; j < 4; ++j) {
                float bv = ebias[((size_t)b * S + q0 + j) * S + col];
                scf[sf][j] = (mk ? NEG : sc[sf][j] * scale) + bv;
            }
        }

        // --- online softmax over rows (16-lane-group shfl reduce) ---
        #pragma unroll
        for (int j = 0; j < 4; ++j) {
            float mx = fmaxf(fmaxf(scf[0][j], scf[1][j]), fmaxf(scf[2][j], scf[3][j]));
            #pragma unroll
            for (int off = 1; off < 16; off <<= 1) mx = fmaxf(mx, __shfl_xor(mx, off));
            float mnew = fmaxf(mrun[j], mx);
            float corr = expf(mrun[j] - mnew);
            mrun[j] = mnew;
            float rs = 0.f;
            #pragma unroll
            for (int sf = 0; sf < 4; ++sf) {
                scf[sf][j] = expf(scf[sf][j] - mnew);
                rs += scf[sf][j];
            }
            #pragma unroll
            for (int off = 1; off < 16; off <<= 1) rs += __shfl_xor(rs, off);
            lsum[j] = lsum[j] * corr + rs;
            #pragma unroll
            for (int df = 0; df < 4; ++df) o[df][j] *= corr;
        }

        // --- P strip to LDS (bf16, XOR swizzle byte^=(r&7)<<4) ---
        #pragma unroll
        for (int sf = 0; sf < 4; ++sf)
            #pragma unroll
            for (int j = 0; j < 4; ++j) {
                int r = lh * 4 + j, c = sf * 16 + lr;
                int off = (r * 128 + c * 2) ^ ((r & 7) << 4);
                *(ushort*)(pstrip + off) = f2bf(scf[sf][j]);
            }

        // --- O += P V ---
        #pragma unroll
        for (int ss = 0; ss < 2; ++ss) {
            int off = (lr * 128 + ss * 64 + lh * 16) ^ ((lr & 7) << 4);
            short8 pa = *(const short8*)(pstrip + off);
            #pragma unroll
            for (int df = 0; df < 4; ++df) {
                short8 vb = *(const short8*)&lds[8192 + (df * 2 + ss) * 512 + lane * 8];
                o[df] = __builtin_amdgcn_mfma_f32_16x16x32_bf16(pa, vb, o[df], 0, 0, 0);
            }
        }

        __syncthreads();   // all waves done reading K/V
        if (kt < 15) stage(kt + 1);
    }

    // --- normalize + write split planes ---
    #pragma unroll
    for (int df = 0; df < 4; ++df)
        #pragma unroll
        for (int j = 0; j < 4; ++j) {
            float val = o[df][j] / lsum[j];
            size_t m = (size_t)b * S + qt * 64 + wid * 16 + lh * 4 + j;
            int colc = h * 64 + df * 16 + lr;
            ushort hh = f2bf(val);
            ohi[m * E + colc] = hh;
            olo[m * E + colc] = f2bf(val - bf2f(hh));
        }
}

// ---------------------------------------------------------------------------
extern "C" void kernel_launch(void* const* d_in, const int* in_sizes, int n_in,
                              void* d_out, int out_size, void* d_ws, size_t ws_size,
                              hipStream_t stream) {
    const float* src  = (const float*)d_in[0];
    const float* eb   = (const float*)d_in[1];
    const unsigned char* mask = (const unsigned char*)d_in[2];
    const float* Wq = (const float*)d_in[3];
    const float* bq = (const float*)d_in[4];
    const float* Wk = (const float*)d_in[5];
    const float* bk = (const float*)d_in[6];
    const float* Wv = (const float*)d_in[7];
    const float* bv = (const float*)d_in[8];
    const float* Wo = (const float*)d_in[9];
    const float* bo = (const float*)d_in[10];
    const float* ln1g = (const float*)d_in[11];
    const float* ln1b = (const float*)d_in[12];
    const float* ln2g = (const float*)d_in[13];
    const float* ln2b = (const float*)d_in[14];
    const float* W1 = (const float*)d_in[15];
    const float* b1 = (const float*)d_in[16];
    const float* W2 = (const float*)d_in[17];
    const float* b2 = (const float*)d_in[18];

    float* x = (float*)d_out;                 // residual stream in d_out

    // ws layout (bytes), total 96,493,568 (same footprint as round 3):
    char* wsb = (char*)d_ws;
    ushort* w_hi = (ushort*)(wsb);
    ushort* w_lo = (ushort*)(wsb + 6291456);
    float*  bqkv = (float*) (wsb + 12582912);
    ushort* h_hi = (ushort*)(wsb + 12607488);
    ushort* h_lo = (ushort*)(wsb + 20996096);
    char*  region = wsb + 29384704;            // 67,108,864 B overlay region
    ushort* qkvh  = (ushort*)(region);                 // [M][1024]
    ushort* qkvl  = (ushort*)(region + 16777216);
    ushort* vT    = (ushort*)(region + 33554432);      // [B*512][S]
    ushort* ab_hi = (ushort*)(region + 41943040);      // [M][512]
    ushort* ab_lo = (ushort*)(region + 50331648);
    ushort* vpl   = (ushort*)(region + 41943040);      // overlay ab_hi (disjoint life)
    ushort* g_hi  = (ushort*)(region);                 // [M][2048] overlay
    ushort* g_lo  = (ushort*)(region + 33554432);

    constexpr size_t OFF_O = 786432;     // ushort offsets within weight plane
    constexpr size_t OFF_1 = 1048576;
    constexpr size_t OFF_2 = 2097152;

    dim3 blk(256);
    copy_kernel<<<2048, blk, 0, stream>>>((const float4*)src, (float4*)x, M * E / 4);
    biaspack_kernel<<<24, blk, 0, stream>>>(bq, bk, bv, bqkv);

    for (int l = 0; l < NL; ++l) {
        const size_t oEE = (size_t)l * E * E;
        wprep_kernel<<<dim3(16, 16), blk, 0, stream>>>(Wq + oEE, w_hi,          w_lo,          512, 512);
        wprep_kernel<<<dim3(16, 16), blk, 0, stream>>>(Wk + oEE, w_hi + 262144, w_lo + 262144, 512, 512);
        wprep_kernel<<<dim3(16, 16), blk, 0, stream>>>(Wv + oEE, w_hi + 524288, w_lo + 524288, 512, 512);
        wprep_kernel<<<dim3(16, 16), blk, 0, stream>>>(Wo + oEE, w_hi + OFF_O,  w_lo + OFF_O,  512, 512);
        wprep_kernel<<<dim3(64, 16), blk, 0, stream>>>(W1 + (size_t)l * E * FF, w_hi + OFF_1, w_lo + OFF_1, 512, 2048);
        wprep_kernel<<<dim3(16, 64), blk, 0, stream>>>(W2 + (size_t)l * FF * E, w_hi + OFF_2, w_lo + OFF_2, 2048, 512);

        // h = LN1(x)
        ln_kernel<<<M, blk, 0, stream>>>(x, ln1g + l * E, ln1b + l * E, h_hi, h_lo);
        // fused QKV (N=1536): Q,K -> split planes; V -> single plane
        gemm_mfma<128, 3><<<dim3(12, 64), blk, 0, stream>>>(h_hi, h_lo, w_hi, w_lo,
            bqkv + l * 1536, (float*)vpl, qkvh, qkvl, 512, 0);
        // V transpose for PV B-operand
        vtrans_kernel<<<dim3(16, 8, 8), blk, 0, stream>>>(vpl, vT);
        // MFMA attention
        attn_mfma<<<dim3(16, 8, 8), blk, 0, stream>>>(qkvh, qkvl, vT, eb, mask, ab_hi, ab_lo);
        // x += attn @ Wo + bo
        gemm_mfma<64, 2><<<dim3(8, 64), blk, 0, stream>>>(ab_hi, ab_lo,
            w_hi + OFF_O, w_lo + OFF_O, bo + l * E, x, nullptr, nullptr, 512, 512);
        // h2 = LN2(x)
        ln_kernel<<<M, blk, 0, stream>>>(x, ln2g + l * E, ln2b + l * E, h_hi, h_lo);
        // gelu(h2 @ W1 + b1) -> split planes
        gemm_mfma<128, 1><<<dim3(16, 64), blk, 0, stream>>>(h_hi, h_lo,
            w_hi + OFF_1, w_lo + OFF_1, b1 + l * FF, nullptr, g_hi, g_lo, 512, 2048);
        // x += ffn @ W2 + b2
        gemm_mfma<64, 2><<<dim3(8, 64), blk, 0, stream>>>(g_hi, g_lo,
            w_hi + OFF_2, w_lo + OFF_2, b2 + l * E, x, nullptr, nullptr, 2048, 512);
    }
}

// Round 6
// 1939.586 us; speedup vs baseline: 2.1592x; 1.0210x over previous
//
#include <hip/hip_runtime.h>
#include <math.h>

// Problem constants
constexpr int B  = 8;
constexpr int S  = 1024;
constexpr int E  = 512;
constexpr int H  = 8;
constexpr int FF = 2048;
constexpr int NL = 4;
constexpr int M  = B * S;          // 8192 rows
constexpr float EPS = 1e-5f;

typedef __attribute__((ext_vector_type(8))) short short8;   // 8 bf16 = 4 VGPR
typedef __attribute__((ext_vector_type(4))) float f32x4;

__device__ __forceinline__ ushort f2bf(float x) {
    union { float f; unsigned u; } c; c.f = x;
    unsigned r = c.u + 0x7FFF + ((c.u >> 16) & 1);   // RNE
    return (ushort)(r >> 16);
}
__device__ __forceinline__ float bf2f(ushort h) {
    union { unsigned u; float f; } c; c.u = ((unsigned)h) << 16; return c.f;
}
// async global->LDS, 16B per lane; LDS dest = base + lane*16 (HW), src per-lane
__device__ __forceinline__ void gload16(const void* g, void* l) {
    __builtin_amdgcn_global_load_lds(
        (const __attribute__((address_space(1))) unsigned*)g,
        (__attribute__((address_space(3))) unsigned*)l, 16, 0, 0);
}

// ---------------------------------------------------------------------------
__global__ __launch_bounds__(256) void copy_kernel(const float4* __restrict__ in,
                                                   float4* __restrict__ out, int n4) {
    int i = blockIdx.x * blockDim.x + threadIdx.x;
    int stride = gridDim.x * blockDim.x;
    for (; i < n4; i += stride) out[i] = in[i];
}

// pack per-layer QKV bias: [L][1536] = concat(bq, bk, bv)
__global__ __launch_bounds__(256) void biaspack_kernel(const float* __restrict__ bq,
                                                       const float* __restrict__ bk,
                                                       const float* __restrict__ bv,
                                                       float* __restrict__ out) {
    int i = blockIdx.x * blockDim.x + threadIdx.x;
    if (i >= NL * 1536) return;
    int l = i / 1536, c = i % 1536;
    float v = (c < 512) ? bq[l * 512 + c]
            : (c < 1024) ? bk[l * 512 + c - 512]
                         : bv[l * 512 + c - 1024];
    out[i] = v;
}

// ---------------------------------------------------------------------------
// Weight prep: W[K][N] fp32 -> hi/lo bf16 planes in [N][K] (transposed) layout.
// ---------------------------------------------------------------------------
__global__ __launch_bounds__(256) void wprep_kernel(const float* __restrict__ W,
                                                    ushort* __restrict__ hi,
                                                    ushort* __restrict__ lo,
                                                    int K, int N) {
    __shared__ float tl[32][33];
    const int n0 = blockIdx.x * 32, k0 = blockIdx.y * 32;
    const int t = threadIdx.x;
    const int tr = t >> 3, tq = t & 7;
    float4 v = *(const float4*)(W + (size_t)(k0 + tr) * N + n0 + tq * 4);
    tl[tr][tq * 4 + 0] = v.x; tl[tr][tq * 4 + 1] = v.y;
    tl[tr][tq * 4 + 2] = v.z; tl[tr][tq * 4 + 3] = v.w;
    __syncthreads();
    const int n = n0 + tr;
    ushort4 hv, lv;
    float a;
    a = tl[tq * 4 + 0][tr]; hv.x = f2bf(a); lv.x = f2bf(a - bf2f(hv.x));
    a = tl[tq * 4 + 1][tr]; hv.y = f2bf(a); lv.y = f2bf(a - bf2f(hv.y));
    a = tl[tq * 4 + 2][tr]; hv.z = f2bf(a); lv.z = f2bf(a - bf2f(hv.z));
    a = tl[tq * 4 + 3][tr]; hv.w = f2bf(a); lv.w = f2bf(a - bf2f(hv.w));
    *(ushort4*)(hi + (size_t)n * K + k0 + tq * 4) = hv;
    *(ushort4*)(lo + (size_t)n * K + k0 + tq * 4) = lv;
}

// ---------------------------------------------------------------------------
// LayerNorm -> split-bf16 hi/lo planes. One block per row.
// ---------------------------------------------------------------------------
__global__ __launch_bounds__(256) void ln_kernel(const float* __restrict__ x,
                                                 const float* __restrict__ g,
                                                 const float* __restrict__ b,
                                                 ushort* __restrict__ ohi,
                                                 ushort* __restrict__ olo) {
    const int row = blockIdx.x;
    const float* xr = x + (size_t)row * E;
    const int c = threadIdx.x * 2;
    float2 v = *(const float2*)(xr + c);
    float s  = v.x + v.y;
    float ss = v.x * v.x + v.y * v.y;
    #pragma unroll
    for (int off = 1; off < 64; off <<= 1) {
        s  += __shfl_xor(s, off);
        ss += __shfl_xor(ss, off);
    }
    __shared__ float red[8];
    const int wid = threadIdx.x >> 6, lane = threadIdx.x & 63;
    if (lane == 0) { red[wid] = s; red[4 + wid] = ss; }
    __syncthreads();
    s  = red[0] + red[1] + red[2] + red[3];
    ss = red[4] + red[5] + red[6] + red[7];
    const float mu   = s / (float)E;
    const float var  = ss / (float)E - mu * mu;
    const float rstd = rsqrtf(var + EPS);
    float2 gg = *(const float2*)(g + c);
    float2 bb = *(const float2*)(b + c);
    float ox = (v.x - mu) * rstd * gg.x + bb.x;
    float oy = (v.y - mu) * rstd * gg.y + bb.y;
    ushort2 hv, lv;
    hv.x = f2bf(ox); lv.x = f2bf(ox - bf2f(hv.x));
    hv.y = f2bf(oy); lv.y = f2bf(oy - bf2f(hv.y));
    *(ushort2*)(ohi + (size_t)row * E + c) = hv;
    *(ushort2*)(olo + (size_t)row * E + c) = lv;
}

// ---------------------------------------------------------------------------
// Split-bf16 MFMA GEMM (verified m97-style structure).
// EPI: 1 = exact GELU -> hi/lo planes, 2 = fp32 residual +=,
//      3 = QKV: cols<1024 -> split planes (ld 1024), cols>=1024 -> V bf16 plane
// ---------------------------------------------------------------------------
template <int BN, int EPI>
__global__ __launch_bounds__(256) void gemm_mfma(
    const ushort* __restrict__ Ahi, const ushort* __restrict__ Alo,
    const ushort* __restrict__ Bhi, const ushort* __restrict__ Blo,
    const float* __restrict__ bias,
    float* __restrict__ outf, ushort* __restrict__ ohi, ushort* __restrict__ olo,
    int K, int ldo)
{
    constexpr int NBF = BN / 16;
    constexpr int NF  = BN / 32;
    constexpr int TL  = 32 + NBF * 4;
    __shared__ ushort lds[16384 + NBF * 2048];

    const int t = threadIdx.x;
    const int lane = t & 63, wid = t >> 6;
    const int wr = wid >> 1, wc = wid & 1;
    const int bn = blockIdx.x, bm = blockIdx.y;
    const int lrow = lane & 15, lhi = lane >> 4;

    f32x4 acc[4][NF];
    #pragma unroll
    for (int i = 0; i < 4; ++i)
        #pragma unroll
        for (int j = 0; j < NF; ++j) acc[i][j] = (f32x4)0.f;

    auto stage = [&](int kt) {
        #pragma unroll
        for (int i = 0; i < TL / 4; ++i) {
            int w = wid * (TL / 4) + i;
            const ushort* src; int dst;
            if (w < 32) {
                int p = w >> 4, mf = (w >> 1) & 7, kk = w & 1;
                int row = bm * 128 + mf * 16 + lrow;
                int k   = kt + kk * 32 + lhi * 8;
                src = (p ? Alo : Ahi) + (size_t)row * K + k;
                dst = (p * 16 + mf * 2 + kk) * 512;
            } else {
                int w2 = w - 32;
                int p = w2 / (NBF * 2), r = w2 % (NBF * 2);
                int nf = r >> 1, kk = r & 1;
                int n = bn * BN + nf * 16 + lrow;
                int k = kt + kk * 32 + lhi * 8;
                src = (p ? Blo : Bhi) + (size_t)n * K + k;
                dst = 16384 + (p * NBF * 2 + nf * 2 + kk) * 512;
            }
            gload16(src, &lds[dst]);
        }
    };

    stage(0);
    const int lrd = lane * 8;
    for (int kt = 0; kt < K; kt += 64) {
        __syncthreads();
        #pragma unroll
        for (int kk = 0; kk < 2; ++kk) {
            short8 ah[4], al[4], bh[NF], bl[NF];
            #pragma unroll
            for (int m_ = 0; m_ < 4; ++m_) {
                int mf = wr * 4 + m_;
                ah[m_] = *(const short8*)&lds[(mf * 2 + kk) * 512 + lrd];
                al[m_] = *(const short8*)&lds[(16 + mf * 2 + kk) * 512 + lrd];
            }
            #pragma unroll
            for (int n_ = 0; n_ < NF; ++n_) {
                int nf = wc * NF + n_;
                bh[n_] = *(const short8*)&lds[16384 + (nf * 2 + kk) * 512 + lrd];
                bl[n_] = *(const short8*)&lds[16384 + (NBF * 2 + nf * 2 + kk) * 512 + lrd];
            }
            #pragma unroll
            for (int m_ = 0; m_ < 4; ++m_)
                #pragma unroll
                for (int n_ = 0; n_ < NF; ++n_) {
                    acc[m_][n_] = __builtin_amdgcn_mfma_f32_16x16x32_bf16(ah[m_], bh[n_], acc[m_][n_], 0, 0, 0);
                    acc[m_][n_] = __builtin_amdgcn_mfma_f32_16x16x32_bf16(ah[m_], bl[n_], acc[m_][n_], 0, 0, 0);
                    acc[m_][n_] = __builtin_amdgcn_mfma_f32_16x16x32_bf16(al[m_], bh[n_], acc[m_][n_], 0, 0, 0);
                }
        }
        __syncthreads();
        if (kt + 64 < K) stage(kt + 64);
    }

    #pragma unroll
    for (int m_ = 0; m_ < 4; ++m_) {
        #pragma unroll
        for (int n_ = 0; n_ < NF; ++n_) {
            const int n  = bn * BN + wc * (BN / 2) + n_ * 16 + lrow;
            const int m0 = bm * 128 + wr * 64 + m_ * 16 + lhi * 4;
            const float bv = bias[n];
            #pragma unroll
            for (int r = 0; r < 4; ++r) {
                const int m = m0 + r;
                float v = acc[m_][n_][r] + bv;
                if (EPI == 1) {
                    float gl = 0.5f * v * (1.0f + erff(v * 0.70710678118654752f));
                    ushort hh = f2bf(gl);
                    ohi[(size_t)m * ldo + n] = hh;
                    olo[(size_t)m * ldo + n] = f2bf(gl - bf2f(hh));
                }
                if (EPI == 2) outf[(size_t)m * ldo + n] += v;
                if (EPI == 3) {
                    if (n < 1024) {
                        ushort hh = f2bf(v);
                        ohi[(size_t)m * 1024 + n] = hh;
                        olo[(size_t)m * 1024 + n] = f2bf(v - bf2f(hh));
                    } else {
                        ((ushort*)outf)[(size_t)m * 512 + (n - 1024)] = f2bf(v);
                    }
                }
            }
        }
    }
}

// ---------------------------------------------------------------------------
// V transpose: vpl [B*S][512] bf16 -> vT [(b*512 + h*64 + d)][S] bf16.
// ---------------------------------------------------------------------------
__global__ __launch_bounds__(256) void vtrans_kernel(const ushort* __restrict__ vpl,
                                                     ushort* __restrict__ vT) {
    __shared__ ushort tl[4096];   // [s 64][c 64], byte = s*128 + c*2, ^((s&7)<<4)
    const int s0 = blockIdx.x * 64, c0 = blockIdx.y * 64, b = blockIdx.z;
    const int t = threadIdx.x;
    {
        const int r = t >> 3, ch = t & 7;
        #pragma unroll
        for (int p = 0; p < 2; ++p) {
            int rr = r + p * 32;
            short8 vv = *(const short8*)(vpl + ((size_t)b * S + s0 + rr) * 512 + c0 + ch * 8);
            int byte = (rr * 128 + ch * 16) ^ ((rr & 7) << 4);
            *(short8*)((char*)tl + byte) = vv;
        }
    }
    __syncthreads();
    {
        const int sj = t & 7, cc0 = t >> 3;
        #pragma unroll
        for (int p = 0; p < 2; ++p) {
            int cc = cc0 + p * 32;
            short8 ov;
            #pragma unroll
            for (int k2 = 0; k2 < 8; ++k2) {
                int s = sj * 8 + k2;
                int byte = (s * 128 + cc * 2) ^ ((s & 7) << 4);
                ov[k2] = (short)*(const ushort*)((const char*)tl + byte);
            }
            *(short8*)(vT + ((size_t)b * 512 + c0 + cc) * S + s0 + sj * 8) = ov;
        }
    }
}

// ---------------------------------------------------------------------------
// MFMA flash attention. Grid (16 qtiles, H, B), 256 thr = 4 waves.
// Per 64-col k-tile: stage K(hi/lo), V, AND the 64x64 fp32 edge-bias tile
// into LDS via global_load_lds (coalesced, pipelined 1 tile ahead).
//   S = Q K^T (Markidis split, 24 MFMA) -> mask/scale/+bias(LDS) -> online
//   softmax (__expf) -> P bf16 swizzled LDS strip -> O += P V (8 MFMA).
// ---------------------------------------------------------------------------
__global__ __launch_bounds__(256) void attn_mfma(
    const ushort* __restrict__ qkh, const ushort* __restrict__ qkl,
    const ushort* __restrict__ vT,
    const float* __restrict__ ebias, const unsigned char* __restrict__ mask,
    ushort* __restrict__ ohi, ushort* __restrict__ olo)
{
    const int qt = blockIdx.x, h = blockIdx.y, b = blockIdx.z;
    const int t = threadIdx.x, lane = t & 63, wid = t >> 6;
    const int lr = lane & 15, lh = lane >> 4;
    const float scale = 0.125f;
    const float NEG = -3.4028234663852886e38f;

    // smem bytes: [0,8192) Khi | [8192,16384) Klo | [16384,24576) V
    //             [24576,40960) ebias fp32 [64][64] | [40960,49152) P strips
    __shared__ __align__(16) char smem[49152];
    ushort* kv = (ushort*)smem;
    float* ebl = (float*)(smem + 24576);
    char* pstrip = smem + 40960 + wid * 2048;

    // Q fragments (A-layout), whole kernel in regs
    short8 qh[2], ql[2];
    {
        const size_t qrow = (size_t)b * S + qt * 64 + wid * 16 + lr;
        const int qc = h * 64 + lh * 8;
        #pragma unroll
        for (int ks = 0; ks < 2; ++ks) {
            qh[ks] = *(const short8*)(qkh + qrow * 1024 + qc + ks * 32);
            ql[ks] = *(const short8*)(qkl + qrow * 1024 + qc + ks * 32);
        }
    }

    f32x4 o[4];
    float mrun[4], lsum[4];
    #pragma unroll
    for (int j = 0; j < 4; ++j) { mrun[j] = -INFINITY; lsum[j] = 0.f; }
    #pragma unroll
    for (int df = 0; df < 4; ++df) o[df] = (f32x4)0.f;

    auto stage = [&](int kt) {
        // K hi/lo + V fragments: 6 gloads per wave
        #pragma unroll
        for (int i = 0; i < 6; ++i) {
            int f = wid * 6 + i;
            const ushort* src; int dst;
            if (f < 8) {                 // K hi
                int sf = f >> 1, ks = f & 1;
                src = qkh + ((size_t)b * S + kt * 64 + sf * 16 + lr) * 1024
                          + 512 + h * 64 + ks * 32 + lh * 8;
                dst = (sf * 2 + ks) * 512;
            } else if (f < 16) {         // K lo
                int f2 = f - 8, sf = f2 >> 1, ks = f2 & 1;
                src = qkl + ((size_t)b * S + kt * 64 + sf * 16 + lr) * 1024
                          + 512 + h * 64 + ks * 32 + lh * 8;
                dst = 4096 + (sf * 2 + ks) * 512;
            } else {                     // V (B-layout from vT)
                int f2 = f - 16, df = f2 >> 1, ss = f2 & 1;
                src = vT + ((size_t)(b * 8 + h) * 64 + df * 16 + lr) * S
                         + kt * 64 + ss * 32 + lh * 8;
                dst = 8192 + (df * 2 + ss) * 512;
            }
            gload16(src, &kv[dst]);
        }
        // ebias tile rows wid*16 .. wid*16+15: 4 gloads per wave (1KB each)
        #pragma unroll
        for (int i = 0; i < 4; ++i) {
            int r0 = wid * 16 + i * 4;
            const float* src = ebias + ((size_t)b * S + qt * 64 + r0 + lh) * S
                                     + kt * 64 + lr * 4;
            gload16(src, (char*)ebl + r0 * 256);
        }
    };

    stage(0);
    for (int kt = 0; kt < 16; ++kt) {
        __syncthreads();   // staged K/V/ebias visible (vmcnt drained at barrier)

        // --- QK^T (split, 3 MFMA per fragment) ---
        f32x4 sc[4];
        #pragma unroll
        for (int sf = 0; sf < 4; ++sf) sc[sf] = (f32x4)0.f;
        #pragma unroll
        for (int ks = 0; ks < 2; ++ks)
            #pragma unroll
            for (int sf = 0; sf < 4; ++sf) {
                short8 kh = *(const short8*)&kv[(sf * 2 + ks) * 512 + lane * 8];
                short8 kl = *(const short8*)&kv[4096 + (sf * 2 + ks) * 512 + lane * 8];
                sc[sf] = __builtin_amdgcn_mfma_f32_16x16x32_bf16(qh[ks], kh, sc[sf], 0, 0, 0);
                sc[sf] = __builtin_amdgcn_mfma_f32_16x16x32_bf16(qh[ks], kl, sc[sf], 0, 0, 0);
                sc[sf] = __builtin_amdgcn_mfma_f32_16x16x32_bf16(ql[ks], kh, sc[sf], 0, 0, 0);
            }

        // --- mask, scale, +edge_bias from LDS ---
        // C-layout: row (in 64-tile) = wid*16 + lh*4 + j, col = sf*16 + lr
        float scf[4][4];
        #pragma unroll
        for (int sf = 0; sf < 4; ++sf) {
            const int col = kt * 64 + sf * 16 + lr;
            const unsigned char mk = mask[(size_t)b * S + col];
            #pragma unroll
            for (int j = 0; j < 4; ++j) {
                float bv = ebl[(wid * 16 + lh * 4 + j) * 64 + sf * 16 + lr];
                scf[sf][j] = (mk ? NEG : sc[sf][j] * scale) + bv;
            }
        }

        // --- online softmax over rows (16-lane-group shfl reduce) ---
        #pragma unroll
        for (int j = 0; j < 4; ++j) {
            float mx = fmaxf(fmaxf(scf[0][j], scf[1][j]), fmaxf(scf[2][j], scf[3][j]));
            #pragma unroll
            for (int off = 1; off < 16; off <<= 1) mx = fmaxf(mx, __shfl_xor(mx, off));
            float mnew = fmaxf(mrun[j], mx);
            float corr = __expf(mrun[j] - mnew);
            mrun[j] = mnew;
            float rs = 0.f;
            #pragma unroll
            for (int sf = 0; sf < 4; ++sf) {
                scf[sf][j] = __expf(scf[sf][j] - mnew);
                rs += scf[sf][j];
            }
            #pragma unroll
            for (int off = 1; off < 16; off <<= 1) rs += __shfl_xor(rs, off);
            lsum[j] = lsum[j] * corr + rs;
            #pragma unroll
            for (int df = 0; df < 4; ++df) o[df][j] *= corr;
        }

        // --- P strip to LDS (bf16, XOR swizzle byte^=(r&7)<<4) ---
        #pragma unroll
        for (int sf = 0; sf < 4; ++sf)
            #pragma unroll
            for (int j = 0; j < 4; ++j) {
                int r = lh * 4 + j, c = sf * 16 + lr;
                int off = (r * 128 + c * 2) ^ ((r & 7) << 4);
                *(ushort*)(pstrip + off) = f2bf(scf[sf][j]);
            }

        // --- O += P V ---
        #pragma unroll
        for (int ss = 0; ss < 2; ++ss) {
            int off = (lr * 128 + ss * 64 + lh * 16) ^ ((lr & 7) << 4);
            short8 pa = *(const short8*)(pstrip + off);
            #pragma unroll
            for (int df = 0; df < 4; ++df) {
                short8 vb = *(const short8*)&kv[8192 + (df * 2 + ss) * 512 + lane * 8];
                o[df] = __builtin_amdgcn_mfma_f32_16x16x32_bf16(pa, vb, o[df], 0, 0, 0);
            }
        }

        __syncthreads();   // all waves done reading K/V/ebias
        if (kt < 15) stage(kt + 1);
    }

    // --- normalize + write split planes ---
    float inv[4];
    #pragma unroll
    for (int j = 0; j < 4; ++j) inv[j] = 1.0f / lsum[j];
    #pragma unroll
    for (int df = 0; df < 4; ++df)
        #pragma unroll
        for (int j = 0; j < 4; ++j) {
            float val = o[df][j] * inv[j];
            size_t m = (size_t)b * S + qt * 64 + wid * 16 + lh * 4 + j;
            int colc = h * 64 + df * 16 + lr;
            ushort hh = f2bf(val);
            ohi[m * E + colc] = hh;
            olo[m * E + colc] = f2bf(val - bf2f(hh));
        }
}

// ---------------------------------------------------------------------------
extern "C" void kernel_launch(void* const* d_in, const int* in_sizes, int n_in,
                              void* d_out, int out_size, void* d_ws, size_t ws_size,
                              hipStream_t stream) {
    const float* src  = (const float*)d_in[0];
    const float* eb   = (const float*)d_in[1];
    const unsigned char* mask = (const unsigned char*)d_in[2];
    const float* Wq = (const float*)d_in[3];
    const float* bq = (const float*)d_in[4];
    const float* Wk = (const float*)d_in[5];
    const float* bk = (const float*)d_in[6];
    const float* Wv = (const float*)d_in[7];
    const float* bv = (const float*)d_in[8];
    const float* Wo = (const float*)d_in[9];
    const float* bo = (const float*)d_in[10];
    const float* ln1g = (const float*)d_in[11];
    const float* ln1b = (const float*)d_in[12];
    const float* ln2g = (const float*)d_in[13];
    const float* ln2b = (const float*)d_in[14];
    const float* W1 = (const float*)d_in[15];
    const float* b1 = (const float*)d_in[16];
    const float* W2 = (const float*)d_in[17];
    const float* b2 = (const float*)d_in[18];

    float* x = (float*)d_out;                 // residual stream in d_out

    // ws layout (bytes), total 96,493,568:
    char* wsb = (char*)d_ws;
    ushort* w_hi = (ushort*)(wsb);
    ushort* w_lo = (ushort*)(wsb + 6291456);
    float*  bqkv = (float*) (wsb + 12582912);
    ushort* h_hi = (ushort*)(wsb + 12607488);
    ushort* h_lo = (ushort*)(wsb + 20996096);
    char*  region = wsb + 29384704;            // 67,108,864 B overlay region
    ushort* qkvh  = (ushort*)(region);                 // [M][1024]
    ushort* qkvl  = (ushort*)(region + 16777216);
    ushort* vT    = (ushort*)(region + 33554432);      // [B*512][S]
    ushort* ab_hi = (ushort*)(region + 41943040);      // [M][512]
    ushort* ab_lo = (ushort*)(region + 50331648);
    ushort* vpl   = (ushort*)(region + 41943040);      // overlay ab_hi (disjoint life)
    ushort* g_hi  = (ushort*)(region);                 // [M][2048] overlay
    ushort* g_lo  = (ushort*)(region + 33554432);

    constexpr size_t OFF_O = 786432;     // ushort offsets within weight plane
    constexpr size_t OFF_1 = 1048576;
    constexpr size_t OFF_2 = 2097152;

    dim3 blk(256);
    copy_kernel<<<2048, blk, 0, stream>>>((const float4*)src, (float4*)x, M * E / 4);
    biaspack_kernel<<<24, blk, 0, stream>>>(bq, bk, bv, bqkv);

    for (int l = 0; l < NL; ++l) {
        const size_t oEE = (size_t)l * E * E;
        wprep_kernel<<<dim3(16, 16), blk, 0, stream>>>(Wq + oEE, w_hi,          w_lo,          512, 512);
        wprep_kernel<<<dim3(16, 16), blk, 0, stream>>>(Wk + oEE, w_hi + 262144, w_lo + 262144, 512, 512);
        wprep_kernel<<<dim3(16, 16), blk, 0, stream>>>(Wv + oEE, w_hi + 524288, w_lo + 524288, 512, 512);
        wprep_kernel<<<dim3(16, 16), blk, 0, stream>>>(Wo + oEE, w_hi + OFF_O,  w_lo + OFF_O,  512, 512);
        wprep_kernel<<<dim3(64, 16), blk, 0, stream>>>(W1 + (size_t)l * E * FF, w_hi + OFF_1, w_lo + OFF_1, 512, 2048);
        wprep_kernel<<<dim3(16, 64), blk, 0, stream>>>(W2 + (size_t)l * FF * E, w_hi + OFF_2, w_lo + OFF_2, 2048, 512);

        // h = LN1(x)
        ln_kernel<<<M, blk, 0, stream>>>(x, ln1g + l * E, ln1b + l * E, h_hi, h_lo);
        // fused QKV (N=1536): Q,K -> split planes; V -> single plane
        gemm_mfma<128, 3><<<dim3(12, 64), blk, 0, stream>>>(h_hi, h_lo, w_hi, w_lo,
            bqkv + l * 1536, (float*)vpl, qkvh, qkvl, 512, 0);
        // V transpose for PV B-operand
        vtrans_kernel<<<dim3(16, 8, 8), blk, 0, stream>>>(vpl, vT);
        // MFMA attention
        attn_mfma<<<dim3(16, 8, 8), blk, 0, stream>>>(qkvh, qkvl, vT, eb, mask, ab_hi, ab_lo);
        // x += attn @ Wo + bo
        gemm_mfma<64, 2><<<dim3(8, 64), blk, 0, stream>>>(ab_hi, ab_lo,
            w_hi + OFF_O, w_lo + OFF_O, bo + l * E, x, nullptr, nullptr, 512, 512);
        // h2 = LN2(x)
        ln_kernel<<<M, blk, 0, stream>>>(x, ln2g + l * E, ln2b + l * E, h_hi, h_lo);
        // gelu(h2 @ W1 + b1) -> split planes
        gemm_mfma<128, 1><<<dim3(16, 64), blk, 0, stream>>>(h_hi, h_lo,
            w_hi + OFF_1, w_lo + OFF_1, b1 + l * FF, nullptr, g_hi, g_lo, 512, 2048);
        // x += ffn @ W2 + b2
        gemm_mfma<64, 2><<<dim3(8, 64), blk, 0, stream>>>(g_hi, g_lo,
            w_hi + OFF_2, w_lo + OFF_2, b2 + l * E, x, nullptr, nullptr, 2048, 512);
    }
}